// Round 15
// baseline (1078.738 us; speedup 1.0000x reference)
//
#include <hip/hip_runtime.h>

typedef unsigned short ushort_t;
typedef unsigned int uint_t;
typedef __attribute__((ext_vector_type(8))) short s8bf;   // 8 x bf16 MFMA fragment
typedef __attribute__((ext_vector_type(4))) float f32x4;  // MFMA accumulator

#define N2 127
#define ACT ((size_t)16*64*127*128)     // activation elements (bf16)
#define HNE ((size_t)16*64*127*64)      // hn elements (bf16)
#define MBW ((size_t)32*3*127*64)       // mailbox words (u32), lives in d_out

__device__ inline float bf_lo(uint_t v){ return __uint_as_float(v << 16); }
__device__ inline float bf_hi(uint_t v){ return __uint_as_float(v & 0xffff0000u); }
__device__ inline ushort_t f2bf(float f){
  uint_t u = __float_as_uint(f);
  uint_t r = ((u >> 16) & 1u) + 0x7fffu;  // RNE
  return (ushort_t)((u + r) >> 16);
}
__device__ inline uint_t cvt_pk_bf16(float lo, float hi){
  uint_t r;
  asm("v_cvt_pk_bf16_f32 %0, %1, %2" : "=v"(r) : "v"(lo), "v"(hi));
  return r;
}
__device__ inline float bf2f(ushort_t h){ return __uint_as_float(((uint_t)h) << 16); }
__device__ inline float frcp(float x){ return __builtin_amdgcn_rcpf(x); }
__device__ inline float sigm(float x){ return frcp(1.f + __expf(-x)); }
__device__ inline float tanhf_(float x){
  float e = __expf(2.f * x);
  return 1.f - 2.f * frcp(1.f + e);
}
__device__ inline void unpack8(uint4 u, float* x){
  x[0]=bf_lo(u.x); x[1]=bf_hi(u.x); x[2]=bf_lo(u.y); x[3]=bf_hi(u.y);
  x[4]=bf_lo(u.z); x[5]=bf_hi(u.z); x[6]=bf_lo(u.w); x[7]=bf_hi(u.w);
}
__device__ inline f32x4 zero4(){ f32x4 v; v[0]=0.f; v[1]=0.f; v[2]=0.f; v[3]=0.f; return v; }
__device__ inline f32x4 splat4(float s){ f32x4 v; v[0]=s; v[1]=s; v[2]=s; v[3]=s; return v; }

// 8 threads/row, 16 elems each
__device__ inline void rowstats16(const float* xr, float& mu, float& rstd){
  float s0=0.f, q0=0.f;
#pragma unroll
  for (int k = 0; k < 16; k++){ s0 += xr[k]; q0 += xr[k]*xr[k]; }
  s0 += __shfl_xor(s0, 1); q0 += __shfl_xor(q0, 1);
  s0 += __shfl_xor(s0, 2); q0 += __shfl_xor(q0, 2);
  s0 += __shfl_xor(s0, 4); q0 += __shfl_xor(q0, 4);
  mu = s0 * 0.0078125f;
  float var = q0 * 0.0078125f - mu*mu;
  rstd = rsqrtf(var + 1e-6f);
}

// ---------------------------------------------------------------------------
// prep_kernel = conv (blocks 0..1023) + pack (1024..3005).  Also zeroes the
// xnf-ready flags (workspace) and the diag mailbox (d_out scratch).
// ---------------------------------------------------------------------------
__global__ __launch_bounds__(256) void prep_kernel(
    const float* __restrict__ im, const float* __restrict__ cb,
    const float* __restrict__ ck,
    const float* __restrict__ w_is, const float* __restrict__ w_ss,
    const float* __restrict__ b_is, const float* __restrict__ b_ss,
    const float* __restrict__ w_oc, const float* __restrict__ w1,
    const float* __restrict__ w2, const float* __restrict__ wh,
    ushort_t* __restrict__ out,
    ushort_t* __restrict__ zWp, ushort_t* __restrict__ wisp,
    ushort_t* __restrict__ wocp,
    float* __restrict__ zbias, float* __restrict__ w1T,
    float* __restrict__ w2T, float* __restrict__ whT,
    uint_t* __restrict__ flg, uint_t* __restrict__ mb)
{
  __shared__ float ims[4][64];   // conv: rows i-3..i, zero-padded for ii<0
  const int tid = threadIdx.x;

  if (blockIdx.x < 1024){
    // ---------------- conv half ----------------
    const int b = blockIdx.x >> 6;
    const int i = blockIdx.x & 63;
    {
      int r = tid >> 6, c = tid & 63;
      int ii = i - 3 + r;
      ims[r][c] = (ii >= 0) ? im[(b*64 + ii)*64 + c] : 0.f;
    }
    const int ch = tid & 127;
    const int jh = tid >> 7;       // 0/1: even/odd j
    float kwreg[24];
#pragma unroll
    for (int tau = 0; tau < 24; tau++){
      int di = (tau < 21) ? (tau/7 - 3) : 0;
      int dj = (tau < 21) ? (tau%7 - 3) : (tau - 24);
      kwreg[tau] = ck[((di+3)*7 + (dj+3))*128 + ch];
    }
    const float cbv = cb[ch];
    __syncthreads();
    ushort_t* orow = out + ((size_t)(b*64 + i)*N2)*128 + ch;
#pragma unroll 1
    for (int jt = 0; jt < 64; jt++){
      int j = jt*2 + jh;
      if (j >= N2) break;
      int base = j - i;
      float acc = cbv;
#pragma unroll
      for (int tau = 0; tau < 24; tau++){
        int di = (tau < 21) ? (tau/7 - 3) : 0;
        int dj = (tau < 21) ? (tau%7 - 3) : (tau - 24);
        int jx = base + dj - di;
        int r = di + 3;
        if (jx >= 0 && jx < 64)
          acc += ims[r][jx] * kwreg[tau];
      }
      orow[(size_t)j*128] = f2bf(acc);
    }
    return;
  }

  // ---------------- pack half ----------------
  int idx = (blockIdx.x - 1024) * 256 + tid;
  if (idx < 131072){                        // zWp (wss): 4 ld x 32768
    int ld = idx >> 15; int r = idx & 32767;
    int e = r & 7, lane = (r >> 3) & 63, ctg = (r >> 9) & 15, kk = r >> 13;
    int k = kk*32 + ((lane >> 4) & 3)*8 + e;
    int n = ctg*16 + (lane & 15);
    float v;
    if (k < 64) v = w_ss[(((size_t)ld*2 + 0)*64 + k)*256 + n];
    else        v = w_ss[(((size_t)ld*2 + 1)*64 + (k-64))*256 + n];
    zWp[idx] = f2bf(v);
  } else if (idx < 262144){                 // wisp: 4 ld x 32768
    int r0 = idx - 131072;
    int ld = r0 >> 15; int r = r0 & 32767;
    int e = r & 7, lane = (r >> 3) & 63, ctg = (r >> 9) & 15, kk = r >> 13;
    int k = kk*32 + ((lane >> 4) & 3)*8 + e;
    int n = ctg*16 + (lane & 15);
    wisp[r0] = f2bf(w_is[((size_t)ld*128 + k)*256 + n]);
  } else if (idx < 294912){                 // wocp: 4 x 8192
    int r0 = idx - 262144;
    int ld = r0 >> 13; int r = r0 & 8191;
    int e = r & 7, lane = (r >> 3) & 63, ctg = (r >> 9) & 7, kk = (r >> 12) & 1;
    int k = kk*32 + ((lane >> 4) & 3)*8 + e;
    int n = ctg*16 + (lane & 15);
    wocp[r0] = f2bf(w_oc[((size_t)ld*64 + k)*128 + n]);
  } else if (idx < 295936){                 // fused z bias
    int r = idx - 294912;
    zbias[r] = b_is[r] + b_ss[r];
  } else if (idx < 300032){                 // w_out1^T (32,128)
    int r = idx - 295936;
    int c = r >> 7, k = r & 127;
    w1T[r] = w1[k*32 + c];
  } else if (idx < 301056){                 // w_out2^T (32,32)
    int r = idx - 300032;
    int c = r >> 5, k = r & 31;
    w2T[r] = w2[k*32 + c];
  } else if (idx < 309248){                 // w_head^T (256,32)
    int r = idx - 301056;
    int o = r >> 5, k = r & 31;
    whT[r] = wh[k*256 + o];
  } else if (idx < 311280){                 // zero xnf-ready flags (2032)
    flg[idx - 309248] = 0u;
  } else if (idx >= 312320 && idx < (int)(312320 + MBW/4)){  // zero mailbox
    ((uint4*)mb)[idx - 312320] = make_uint4(0u, 0u, 0u, 0u);
  }
}

// write_frags (512-thread, AGENT scope -> MALL write-through): 8 wave-groups
__device__ inline void write_frags512A(const ushort_t* __restrict__ XN,
                                       ushort_t* __restrict__ dst, int tid){
  int lane = tid & 63, t8 = tid >> 6;
  int quad = (lane >> 4) & 3, l16 = lane & 15;
  int kk = t8 >> 1, rh = (t8 & 1)*2;
#pragma unroll
  for (int i = 0; i < 2; i++){
    int rt = rh + i;
    uint4 v = *(const uint4*)&XN[(size_t)(rt*16 + l16)*136 + kk*32 + quad*8];
    uint_t* d = (uint_t*)(dst + (size_t)((kk*4 + rt)*64 + lane)*8);
    __hip_atomic_store(d+0, v.x, __ATOMIC_RELAXED, __HIP_MEMORY_SCOPE_AGENT);
    __hip_atomic_store(d+1, v.y, __ATOMIC_RELAXED, __HIP_MEMORY_SCOPE_AGENT);
    __hip_atomic_store(d+2, v.z, __ATOMIC_RELAXED, __HIP_MEMORY_SCOPE_AGENT);
    __hip_atomic_store(d+3, v.w, __ATOMIC_RELAXED, __HIP_MEMORY_SCOPE_AGENT);
  }
}

// write_frags (512-thread, plain) -- for cross-launch consumers
__device__ inline void write_frags512(const ushort_t* __restrict__ XN,
                                      ushort_t* __restrict__ dst, int tid){
  int lane = tid & 63, t8 = tid >> 6;
  int quad = (lane >> 4) & 3, l16 = lane & 15;
  int kk = t8 >> 1, rh = (t8 & 1)*2;
#pragma unroll
  for (int i = 0; i < 2; i++){
    int rt = rh + i;
    uint4 v = *(const uint4*)&XN[(size_t)(rt*16 + l16)*136 + kk*32 + quad*8];
    *(uint4*)(dst + (size_t)((kk*4 + rt)*64 + lane)*8) = v;
  }
}

// LN a 16-elem row-eighth into XN (512-thread layout)
__device__ inline void ln_to_XN16(ushort_t* __restrict__ XN, int row, int lq,
                                  const float* xr, float mu, float rstd,
                                  const float* __restrict__ ln_s,
                                  const float* __restrict__ ln_b, int ld){
  uint_t o[8];
#pragma unroll
  for (int k2 = 0; k2 < 8; k2++){
    int c = lq*16 + 2*k2;
    float a = (xr[2*k2]   - mu)*rstd*ln_s[ld*128 + c]     + ln_b[ld*128 + c];
    float b = (xr[2*k2+1] - mu)*rstd*ln_s[ld*128 + c + 1] + ln_b[ld*128 + c + 1];
    o[k2] = cvt_pk_bf16(a, b);
  }
  uint4* dst = (uint4*)&XN[(size_t)row*136 + lq*16];
  dst[0] = make_uint4(o[0], o[1], o[2], o[3]);
  dst[1] = make_uint4(o[4], o[5], o[6], o[7]);
}

// ---------------------------------------------------------------------------
// stage0 body (512 threads): LN both dirs -> xnf frags (AGENT) + ready flag.
// ---------------------------------------------------------------------------
__device__ void stage0_body(int bj, int tid, const ushort_t* __restrict__ Xbuf,
    const float* __restrict__ ln_s, const float* __restrict__ ln_b,
    ushort_t* __restrict__ xnfL, ushort_t* __restrict__ xnfR,
    uint_t* __restrict__ flg, uint_t fstamp, char* smem)
{
  ushort_t* XN = (ushort_t*)smem;                  // 17408 B
  const int b = bj / 127, j = bj - b*127;
  const int row = tid >> 3, lq = tid & 7;

  float xr[16];
  {
    const uint4* p = (const uint4*)(Xbuf + ((size_t)(b*64 + row)*N2 + j)*128 + lq*16);
    unpack8(p[0], xr); unpack8(p[1], xr+8);
  }
  float mu, rstd;
  rowstats16(xr, mu, rstd);

  ln_to_XN16(XN, row, lq, xr, mu, rstd, ln_s, ln_b, 0);
  __syncthreads();
  write_frags512A(XN, xnfL + (size_t)bj*8192, tid);
  __syncthreads();
  ln_to_XN16(XN, row, lq, xr, mu, rstd, ln_s, ln_b, 1);
  __syncthreads();
  write_frags512A(XN, xnfR + (size_t)bj*8192, tid);
  asm volatile("s_waitcnt vmcnt(0)" ::: "memory");
  __syncthreads();
  if (tid == 0)
    __hip_atomic_store(&flg[bj], fstamp, __ATOMIC_RELAXED, __HIP_MEMORY_SCOPE_AGENT);
}

// ---------------------------------------------------------------------------
// stage12 body (512 threads).  mode 1: woc epilogue both dirs + m-shift ->
// Xbuf (in place), then LN next layer -> xnf frags (AGENT if flg) + flag.
// mode 2: stops after Xbuf write (plain stores, cross-launch consumer).
// ---------------------------------------------------------------------------
__device__ void stage12_body(int bj, int tid, int mode, int woclyr, int lnlyr,
    ushort_t* __restrict__ Xbuf,
    const ushort_t* __restrict__ hnL, const ushort_t* __restrict__ hnR,
    const ushort_t* __restrict__ wocp, const float* __restrict__ b_oc,
    const float* __restrict__ ln_s, const float* __restrict__ ln_b,
    ushort_t* __restrict__ xnfL, ushort_t* __restrict__ xnfR,
    uint_t* __restrict__ flg, uint_t fstamp, char* smem)
{
  float* Xout  = (float*)smem;                     // 33792 B
  ushort_t* XN = (ushort_t*)(smem + 33792);        // 17408 B
  ushort_t* XNh= (ushort_t*)(smem + 51200);        //  9216 B (total 60416)

  const int b = bj / 127, j = bj - b*127;
  const int w8 = tid >> 6;                       // wave: 16-col group
  const int lane = tid & 63, quad = (lane >> 4) & 3, l16 = lane & 15;
  const int row = tid >> 3, lq = tid & 7;        // 8 threads/row

  float xr[16];
  {
    const uint4* p = (const uint4*)(Xbuf + ((size_t)(b*64 + row)*N2 + j)*128 + lq*16);
    unpack8(p[0], xr); unpack8(p[1], xr+8);
  }
  float mu, rstd;
  rowstats16(xr, mu, rstd);

#pragma unroll 1
  for (int s = 0; s < 2; s++){
    const int ld = woclyr*2 + s;
    ln_to_XN16(XN, row, lq, xr, mu, rstd, ln_s, ln_b, ld);   // residual xn
    {
      const ushort_t* hp = s ? hnR : hnL;
      const uint4* p = (const uint4*)(hp + ((size_t)(b*64 + row)*N2 + j)*64 + lq*8);
      *(uint4*)&XNh[(size_t)row*72 + lq*8] = p[0];
    }
    __syncthreads();
    s8bf bw[2];
#pragma unroll
    for (int kk = 0; kk < 2; kk++)
      bw[kk] = *(const s8bf*)(wocp + (size_t)ld*8192 + (size_t)(((kk*8 + w8)*64 + lane)*8));
    f32x4 a2[4];
#pragma unroll
    for (int rt = 0; rt < 4; rt++) a2[rt] = zero4();
#pragma unroll
    for (int kk = 0; kk < 2; kk++)
#pragma unroll
      for (int rt = 0; rt < 4; rt++){
        s8bf a = *(const s8bf*)&XNh[(size_t)(rt*16 + l16)*72 + kk*32 + quad*8];
        a2[rt] = __builtin_amdgcn_mfma_f32_16x16x32_bf16(a, bw[kk], a2[rt], 0, 0, 0);
      }
    const float bv = b_oc[ld*128 + w8*16 + l16];
    const int col = w8*16 + l16;
#pragma unroll
    for (int rt = 0; rt < 4; rt++)
#pragma unroll
      for (int r = 0; r < 4; r++){
        int rr = rt*16 + quad*4 + r;
        float v = a2[rt][r] + bv + bf2f(XN[(size_t)rr*136 + col]);
        if (s == 0) Xout[(size_t)rr*132 + col] = v;
        else if (rr < 63) Xout[(size_t)(rr + 1)*132 + col] += v;  // m-shift
      }
    __syncthreads();
  }

  float xo[16];
#pragma unroll
  for (int k = 0; k < 16; k++) xo[k] = Xout[(size_t)row*132 + lq*16 + k];
  {
    uint_t o[8];
#pragma unroll
    for (int k = 0; k < 8; k++) o[k] = cvt_pk_bf16(xo[2*k], xo[2*k + 1]);
    uint4* dst = (uint4*)(Xbuf + ((size_t)(b*64 + row)*N2 + j)*128 + lq*16);
    dst[0] = make_uint4(o[0], o[1], o[2], o[3]);
    dst[1] = make_uint4(o[4], o[5], o[6], o[7]);
  }
  if (mode == 2) return;

  float mu2, rstd2;
  rowstats16(xo, mu2, rstd2);
  ln_to_XN16(XN, row, lq, xo, mu2, rstd2, ln_s, ln_b, lnlyr*2 + 0);
  __syncthreads();
  write_frags512A(XN, xnfL + (size_t)bj*8192, tid);
  __syncthreads();
  ln_to_XN16(XN, row, lq, xo, mu2, rstd2, ln_s, ln_b, lnlyr*2 + 1);
  __syncthreads();
  write_frags512A(XN, xnfR + (size_t)bj*8192, tid);
  asm volatile("s_waitcnt vmcnt(0)" ::: "memory");
  __syncthreads();
  if (tid == 0)
    __hip_atomic_store(&flg[bj], fstamp, __ATOMIC_RELAXED, __HIP_MEMORY_SCOPE_AGENT);
}

// ---------------------------------------------------------------------------
// Diagonal LSTM body (256 threads; proven 161.7us structure + tile-ready
// flag polling for in-kernel producers).  Exactly 128 __syncthreads.
// ---------------------------------------------------------------------------
__device__ void diag_body(int blk, int tid,
    const ushort_t* __restrict__ xnfL, const ushort_t* __restrict__ xnfR,
    ushort_t* __restrict__ hnL, ushort_t* __restrict__ hnR,
    const ushort_t* __restrict__ zWp, const ushort_t* __restrict__ wisp,
    const float* __restrict__ zbias, const float* __restrict__ h0, int layer,
    uint_t* __restrict__ mb, const uint_t* __restrict__ flg, uint_t fstamp,
    ushort_t* __restrict__ Ap /* 2*16*136 ushort in LDS */)
{
  const int g = blk & 3;                  // row group
  const int b = (blk >> 2) & 15;
  const int d = blk >> 6;
  const int ld = layer*2 + d;
  const ushort_t* xnf = d ? xnfR : xnfL;
  ushort_t* hp = d ? hnR : hnL;

  const int w = tid >> 6;
  const int lane = tid & 63;
  const int quad = lane >> 4;
  const int l16 = lane & 15;
  const int cg = w*16 + l16;

  s8bf bss[4][4], bis[4][4];
#pragma unroll
  for (int kk = 0; kk < 4; kk++)
#pragma unroll
    for (int ct = 0; ct < 4; ct++){
      size_t fo = (size_t)(((kk*16 + (w + 4*ct))*64 + lane)*8);
      bss[kk][ct] = *(const s8bf*)(zWp  + (size_t)ld*32768 + fo);
      bis[kk][ct] = *(const s8bf*)(wisp + (size_t)ld*32768 + fo);
    }
  float zb[4];
#pragma unroll
  for (int ct = 0; ct < 4; ct++) zb[ct] = zbias[ld*256 + ct*64 + cg];

  float c_reg[4] = {0.f, 0.f, 0.f, 0.f};

  { // init both A buffers
    int r2 = tid >> 4, q8 = tid & 15;
    const float* h0p = h0 + ld*64;
#pragma unroll
    for (int k = 0; k < 8; k++){
      int c = q8*8 + k;
      ushort_t hb = f2bf(h0p[c & 63]);
      ushort_t v;
      if (c < 64) v = (g == 0 && r2 == 0) ? (ushort_t)0 : hb;
      else        v = hb;
      Ap[(0*16 + r2)*136 + c] = v;
      Ap[(1*16 + r2)*136 + c] = v;
    }
  }

  const int stp8 = d ? -8192 : 8192;
  const ushort_t* xbase = xnf + ((size_t)b*127 + (d ? 126 : 0))*8192;
  const uint_t* fbase = flg + b*127;

  // wait tile 0 ready, then zxa(0)
  {
    const uint_t* f0 = fbase + (d ? 126 : 0);
    while (__hip_atomic_load(f0, __ATOMIC_RELAXED, __HIP_MEMORY_SCOPE_AGENT) < fstamp) {}
    asm volatile("" ::: "memory");
  }
  uint4 xf[4];
#pragma unroll
  for (int kk = 0; kk < 4; kk++)
    xf[kk] = *(const uint4*)(xbase + (size_t)((kk*4 + g)*64 + lane)*8);

  f32x4 acc[4];
#pragma unroll
  for (int ct = 0; ct < 4; ct++) acc[ct] = splat4(zb[ct]);
#pragma unroll
  for (int kk = 0; kk < 4; kk++){
    s8bf a = *(const s8bf*)&xf[kk];
#pragma unroll
    for (int ct = 0; ct < 4; ct++)
      acc[ct] = __builtin_amdgcn_mfma_f32_16x16x32_bf16(a, bis[kk][ct], acc[ct], 0, 0, 0);
  }
  // wait tile 1 ready, prefetch it
  {
    const uint_t* f1 = fbase + (d ? 125 : 1);
    while (__hip_atomic_load(f1, __ATOMIC_RELAXED, __HIP_MEMORY_SCOPE_AGENT) < fstamp) {}
    asm volatile("" ::: "memory");
  }
  const ushort_t* pfp = xbase + stp8;
#pragma unroll
  for (int kk = 0; kk < 4; kk++)
    xf[kk] = *(const uint4*)(pfp + (size_t)((kk*4 + g)*64 + lane)*8);
  pfp += stp8;
  const uint_t* fpf = fbase + (d ? 124 : 2);   // flag for tile t+2
  const int fstep = d ? -1 : 1;

  const int dj64 = d ? -64 : 64;
  ushort_t* hlane = hp + ((size_t)(b*64 + g*16 + quad*4)*N2 + (d ? 126 : 0))*64 + cg;

  const int bd = b*2 + d;
  uint_t* mbOut = mb + ((size_t)(bd*3 + g)*127)*64;                 // g<3
  const uint_t* mbIn = mb + ((size_t)(bd*3 + (g > 0 ? g - 1 : 0))*127)*64;
  const uint_t stampBase = (uint_t)layer * 127u;
  const bool isProd = (g < 3);
  const bool isCons = (g > 0) && (w == 1);

  __syncthreads();  // barrier #1: A init visible

#pragma unroll 1
  for (int t = 0; t < 127; t++){
    const int pr = t & 1, pn = pr ^ 1;
    const uint_t stamp = stampBase + (uint_t)t + 1u;
    const bool doFetch = isCons && (t < 126);

    // early polls: mailbox slot t, and ready-flag for tile t+2
    uint_t pv = 0;
    if (doFetch)
      pv = __hip_atomic_load(mbIn + (size_t)t*64 + lane,
                             __ATOMIC_RELAXED, __HIP_MEMORY_SCOPE_AGENT);
    uint_t fv = 0xffffffffu;
    if (t < 125)
      fv = __hip_atomic_load(fpf, __ATOMIC_RELAXED, __HIP_MEMORY_SCOPE_AGENT);

    // ---- phase A: acc += [hprev|h] @ wss ----
#pragma unroll
    for (int kk = 0; kk < 4; kk++){
      s8bf af = *(const s8bf*)&Ap[(pr*16 + l16)*136 + kk*32 + quad*8];
#pragma unroll
      for (int ct = 0; ct < 4; ct++)
        acc[ct] = __builtin_amdgcn_mfma_f32_16x16x32_bf16(af, bss[kk][ct], acc[ct], 0, 0, 0);
    }

    // ---- phase B: gates + fire-and-forget boundary publish ----
#pragma unroll
    for (int r = 0; r < 4; r++){
      float fg = sigm(acc[0][r]);
      float ig = sigm(acc[1][r]);
      float og = sigm(acc[2][r]);
      float gg = tanhf_(acc[3][r]);
      float cn = fg*c_reg[r] + ig*gg;
      c_reg[r] = cn;
      float hn = og * tanhf_(cn);
      int rr = quad*4 + r;
      ushort_t hb = f2bf(hn);
      Ap[(pn*16 + rr)*136 + 64 + cg] = hb;
      if (rr < 15) Ap[(pn*16 + rr + 1)*136 + cg] = hb;
      hlane[(size_t)r*8128] = hb;
      if (r == 3 && isProd && quad == 3 && t < 126)
        __hip_atomic_store(mbOut + (size_t)t*64 + cg,
                           (stamp << 16) | (uint_t)hb,
                           __ATOMIC_RELAXED, __HIP_MEMORY_SCOPE_AGENT);
    }
    hlane += dj64;

    // ---- phase B: zxa(t+1) = xn(t+1)@wis + zbias ----
    if (t < 126){
#pragma unroll
      for (int ct = 0; ct < 4; ct++) acc[ct] = splat4(zb[ct]);
#pragma unroll
      for (int kk = 0; kk < 4; kk++){
        s8bf a = *(const s8bf*)&xf[kk];
#pragma unroll
        for (int ct = 0; ct < 4; ct++)
          acc[ct] = __builtin_amdgcn_mfma_f32_16x16x32_bf16(a, bis[kk][ct], acc[ct], 0, 0, 0);
      }
      if (t < 125){
        if (fv < fstamp){
          while (__hip_atomic_load(fpf, __ATOMIC_RELAXED, __HIP_MEMORY_SCOPE_AGENT) < fstamp) {}
        }
        asm volatile("" ::: "memory");
#pragma unroll
        for (int kk = 0; kk < 4; kk++)
          xf[kk] = *(const uint4*)(pfp + (size_t)((kk*4 + g)*64 + lane)*8);
        pfp += stp8;
        fpf += fstep;
      }
    }

    // ---- consumer: stamped mailbox check ----
    if (doFetch){
      while (!__all((pv >> 16) == stamp))
        pv = __hip_atomic_load(mbIn + (size_t)t*64 + lane,
                               __ATOMIC_RELAXED, __HIP_MEMORY_SCOPE_AGENT);
      Ap[(pn*16 + 0)*136 + lane] = (ushort_t)(pv & 0xffffu);
    }

    __syncthreads(); // barriers #2..#128
  }
}

// ---------------------------------------------------------------------------
// Fused producer-consumer launches.  Blocks 0..127 = diag; 128..2159 = stage.
// Diag blocks use only the first 256 threads; the idle 4 waves execute a
// matched count (128) of barriers.  Producers never wait on consumers, and
// 128 spinning blocks can never fill all resident slots -> deadlock-free.
// ---------------------------------------------------------------------------
__global__ __launch_bounds__(512, 1) void sd0_kernel(
    ushort_t* __restrict__ Xbuf,
    const float* __restrict__ ln_s, const float* __restrict__ ln_b,
    ushort_t* __restrict__ xnfL, ushort_t* __restrict__ xnfR,
    ushort_t* __restrict__ hnL, ushort_t* __restrict__ hnR,
    const ushort_t* __restrict__ zWp, const ushort_t* __restrict__ wisp,
    const float* __restrict__ zbias, const float* __restrict__ h0,
    uint_t* __restrict__ mb, uint_t* __restrict__ flg)
{
  __shared__ __align__(16) char smem[17408];
  if (blockIdx.x < 128){
    if (threadIdx.x >= 256){
#pragma unroll 1
      for (int t = 0; t < 128; t++) __syncthreads();
      return;
    }
    diag_body(blockIdx.x, threadIdx.x, xnfL, xnfR, hnL, hnR, zWp, wisp,
              zbias, h0, 0, mb, flg, 1u, (ushort_t*)smem);
    return;
  }
  stage0_body(blockIdx.x - 128, threadIdx.x, Xbuf, ln_s, ln_b,
              xnfL, xnfR, flg, 1u, smem);
}

__global__ __launch_bounds__(512, 1) void sd1_kernel(
    ushort_t* __restrict__ Xbuf,
    const ushort_t* __restrict__ hn0L, const ushort_t* __restrict__ hn0R,
    const ushort_t* __restrict__ wocp, const float* __restrict__ b_oc,
    const float* __restrict__ ln_s, const float* __restrict__ ln_b,
    ushort_t* __restrict__ xnfL, ushort_t* __restrict__ xnfR,
    ushort_t* __restrict__ hn1L, ushort_t* __restrict__ hn1R,
    const ushort_t* __restrict__ zWp, const ushort_t* __restrict__ wisp,
    const float* __restrict__ zbias, const float* __restrict__ h0,
    uint_t* __restrict__ mb, uint_t* __restrict__ flg)
{
  __shared__ __align__(16) char smem[60416];
  if (blockIdx.x < 128){
    if (threadIdx.x >= 256){
#pragma unroll 1
      for (int t = 0; t < 128; t++) __syncthreads();
      return;
    }
    diag_body(blockIdx.x, threadIdx.x, xnfL, xnfR, hn1L, hn1R, zWp, wisp,
              zbias, h0, 1, mb, flg, 2u, (ushort_t*)smem);
    return;
  }
  stage12_body(blockIdx.x - 128, threadIdx.x, 1, 0, 1, Xbuf, hn0L, hn0R,
               wocp, b_oc, ln_s, ln_b, xnfL, xnfR, flg, 2u, smem);
}

// stage12 mode-2 standalone (plain stores; consumed by head across boundary)
__global__ __launch_bounds__(512, 1) void stage2_kernel(
    ushort_t* __restrict__ Xbuf,
    const ushort_t* __restrict__ hnL, const ushort_t* __restrict__ hnR,
    const ushort_t* __restrict__ wocp, const float* __restrict__ b_oc,
    const float* __restrict__ ln_s, const float* __restrict__ ln_b)
{
  __shared__ __align__(16) char smem[60416];
  stage12_body(blockIdx.x, threadIdx.x, 2, 1, 0, Xbuf, hnL, hnR,
               wocp, b_oc, ln_s, ln_b, nullptr, nullptr, nullptr, 0u, smem);
}

// ---------------------------------------------------------------------------
// Head (512 threads): unskew + (128->32)->(32->32)->(32->256), fp32 vector.
// ---------------------------------------------------------------------------
__global__ __launch_bounds__(512) void head_kernel(
    const ushort_t* __restrict__ xfin,
    const float* __restrict__ w1T, const float* __restrict__ b1,
    const float* __restrict__ w2T, const float* __restrict__ b2,
    const float* __restrict__ whT, const float* __restrict__ bh,
    float* __restrict__ out)
{
  __shared__ float xf[64][132];
  __shared__ float v1[64][36];
  __shared__ float v2[64][36];
  int tid = threadIdx.x;
  int b = blockIdx.x >> 6, i = blockIdx.x & 63;
  {
    int jj = tid >> 3, q = tid & 7;
    size_t base = ((size_t)(b*64 + i)*N2 + (i + jj))*128 + q*16;  // unskew
    const uint4* pL = (const uint4*)(xfin + base);
    float x[16];
    unpack8(pL[0], x); unpack8(pL[1], x+8);
#pragma unroll
    for (int k = 0; k < 16; k++) xf[jj][q*16 + k] = x[k];
  }
  __syncthreads();
  {
    int c1 = tid & 31, jg = tid >> 5;     // 16 groups x 4 rows
    float accv[4];
#pragma unroll
    for (int q = 0; q < 4; q++) accv[q] = b1[c1];
#pragma unroll 1
    for (int kc = 0; kc < 4; kc++){
      float wr[32];
      const float4* wp = (const float4*)(w1T + c1*128 + kc*32);
#pragma unroll
      for (int kk = 0; kk < 8; kk++) ((float4*)wr)[kk] = wp[kk];
#pragma unroll
      for (int jj2 = 0; jj2 < 4; jj2++){
        int jr = jg*4 + jj2;
        float a0=0.f,a1=0.f,a2=0.f,a3=0.f;
#pragma unroll
        for (int kk = 0; kk < 8; kk++){
          float4 xv = *(const float4*)&xf[jr][kc*32 + kk*4];
          a0 += xv.x*wr[kk*4]; a1 += xv.y*wr[kk*4+1]; a2 += xv.z*wr[kk*4+2]; a3 += xv.w*wr[kk*4+3];
        }
        accv[jj2] += (a0+a1)+(a2+a3);
      }
    }
#pragma unroll
    for (int jj2 = 0; jj2 < 4; jj2++) v1[jg*4 + jj2][c1] = accv[jj2];
  }
  __syncthreads();
  {
    int c2 = tid & 31, jg = tid >> 5;     // 16 groups x 4 rows
    float wr[32];
    const float4* wp = (const float4*)(w2T + c2*32);
#pragma unroll
    for (int kk = 0; kk < 8; kk++) ((float4*)wr)[kk] = wp[kk];
#pragma unroll
    for (int jj2 = 0; jj2 < 4; jj2++){
      int jr = jg*4 + jj2;
      float a0=0.f,a1=0.f,a2=0.f,a3=0.f;
#pragma unroll
      for (int kk = 0; kk < 8; kk++){
        float4 xv = *(const float4*)&v1[jr][kk*4];
        a0 += xv.x*wr[kk*4]; a1 += xv.y*wr[kk*4+1]; a2 += xv.z*wr[kk*4+2]; a3 += xv.w*wr[kk*4+3];
      }
      v2[jr][c2] = b2[c2] + (a0+a1)+(a2+a3);
    }
  }
  __syncthreads();
  {
    int o = tid & 255, jh = tid >> 8;     // two halves of the jr range
    float wr[32];
    const float4* wp = (const float4*)(whT + o*32);
#pragma unroll
    for (int kk = 0; kk < 8; kk++) ((float4*)wr)[kk] = wp[kk];
    float bo = bh[o];
#pragma unroll 1
    for (int jr2 = 0; jr2 < 32; jr2++){
      int jr = jh*32 + jr2;
      float a0=0.f,a1=0.f,a2=0.f,a3=0.f;
#pragma unroll
      for (int kk = 0; kk < 8; kk++){
        float4 xv = *(const float4*)&v2[jr][kk*4];
        a0 += xv.x*wr[kk*4]; a1 += xv.y*wr[kk*4+1]; a2 += xv.z*wr[kk*4+2]; a3 += xv.w*wr[kk*4+3];
      }
      out[(((size_t)b*64 + i)*64 + jr)*256 + o] = bo + (a0+a1)+(a2+a3);
    }
  }
}

// ---------------------------------------------------------------------------
extern "C" void kernel_launch(void* const* d_in, const int* in_sizes, int n_in,
                              void* d_out, int out_size, void* d_ws, size_t ws_size,
                              hipStream_t stream)
{
  const float* im   = (const float*)d_in[0];
  const float* ck   = (const float*)d_in[1];
  const float* cb   = (const float*)d_in[2];
  const float* ln_s = (const float*)d_in[3];
  const float* ln_b = (const float*)d_in[4];
  const float* w_is = (const float*)d_in[5];
  const float* b_is = (const float*)d_in[6];
  const float* w_ss = (const float*)d_in[7];
  const float* b_ss = (const float*)d_in[8];
  const float* w_oc = (const float*)d_in[9];
  const float* b_oc = (const float*)d_in[10];
  const float* h0   = (const float*)d_in[11];
  const float* w1   = (const float*)d_in[12];
  const float* b1   = (const float*)d_in[13];
  const float* w2   = (const float*)d_in[14];
  const float* b2   = (const float*)d_in[15];
  const float* wh   = (const float*)d_in[16];
  const float* bh   = (const float*)d_in[17];

  // Workspace: 133,734,336 B (<= proven 133,828,608).  hn double-buffered
  // per layer so sd1's diag writes can't race stage12(1)'s layer-0 reads.
  ushort_t* Xbuf = (ushort_t*)d_ws;        // X0 -> X1 (aliased) -> xfin
  ushort_t* xnfL = Xbuf + ACT;             // xn fragment files (per layer)
  ushort_t* xnfR = xnfL + ACT;
  ushort_t* hn0L = xnfR + ACT;             // layer-0 hn
  ushort_t* hn0R = hn0L + HNE;
  ushort_t* hn1L = hn0R + HNE;             // layer-1 hn
  ushort_t* hn1R = hn1L + HNE;
  ushort_t* zWp  = hn1R + HNE;             // wss frags  (131072 el)
  ushort_t* wisp = zWp + 131072;           // wis frags  (131072 el)
  ushort_t* wocp = wisp + 131072;          // woc frags  (32768 el)
  float* zbias = (float*)(wocp + 32768);
  float* w1T   = zbias + 1024;
  float* w2T   = w1T + 4096;
  float* whT   = w2T + 1024;
  uint_t* flg  = (uint_t*)(whT + 8192);    // 2032 xnf-ready flags
  uint_t* mb   = (uint_t*)d_out;           // stamped handoff mailbox (3.1 MB)

  prep_kernel<<<3006, 256, 0, stream>>>(im, cb, ck, w_is, w_ss, b_is, b_ss,
                                        w_oc, w1, w2, wh, Xbuf,
                                        zWp, wisp, wocp, zbias, w1T, w2T, whT,
                                        flg, mb);
  sd0_kernel<<<2160, 512, 0, stream>>>(Xbuf, ln_s, ln_b, xnfL, xnfR,
                                       hn0L, hn0R, zWp, wisp, zbias, h0, mb, flg);
  sd1_kernel<<<2160, 512, 0, stream>>>(Xbuf, hn0L, hn0R, wocp, b_oc, ln_s, ln_b,
                                       xnfL, xnfR, hn1L, hn1R, zWp, wisp,
                                       zbias, h0, mb, flg);
  stage2_kernel<<<2032, 512, 0, stream>>>(Xbuf, hn1L, hn1R, wocp, b_oc, ln_s, ln_b);
  head_kernel<<<1024, 512, 0, stream>>>(Xbuf, w1T, b1, w2T, b2, whT, bh, (float*)d_out);
}